// Round 1
// 598.656 us; speedup vs baseline: 1.0051x; 1.0051x over previous
//
#include <hip/hip_runtime.h>

typedef _Float16 f16;
typedef _Float16 f16x8 __attribute__((ext_vector_type(8)));
typedef _Float16 f16x4 __attribute__((ext_vector_type(4)));
typedef float f32x4 __attribute__((ext_vector_type(4)));
typedef float f32x4a __attribute__((ext_vector_type(4), aligned(4)));

#define B_DIM 16
#define T_DIM 243
#define J_DIM 17
#define C_DIM 256
#define H_DIM 8
#define HD_DIM 32
#define M_DIM (B_DIM * T_DIM * J_DIM)   // 66096
#define NSLICE (B_DIM * H_DIM * J_DIM)  // 2176
#define TJ (T_DIM * J_DIM)              // 4131

// workspace layout, in f16 units
#define QP_OFF 0ull
#define KP_OFF ((unsigned long long)NSLICE * T_DIM * HD_DIM)          // 16,920,576
#define VPT_OFF (2ull * KP_OFF)                                        // 33,841,152
#define O_OFF (VPT_OFF + (unsigned long long)NSLICE * HD_DIM * 256)    // + 17,825,792
#define WF_OFF (O_OFF + (unsigned long long)M_DIM * C_DIM)             // + 16,920,576
#define ATTN_SZ ((unsigned long long)NSLICE * T_DIM * T_DIM)           // 128,490,624

// XOR swizzle: keeps 8-f16 (16B) blocks contiguous, spreads rows across banks
// (only flips col bits 3..5, so 4-f16 and 8-f16 aligned blocks stay contiguous)
#define SWZ(row, col) ((col) ^ (((row) & 7) << 3))

__global__ __launch_bounds__(256)
void wconv_kernel(const float* __restrict__ Wq, const float* __restrict__ Wk,
                  const float* __restrict__ Wv, const float* __restrict__ Wp,
                  f16* __restrict__ wf)
{
    int i = blockIdx.x * 256 + threadIdx.x;  // 0 .. 4*65536-1
    const float* src = (i < 65536) ? Wq : (i < 131072) ? Wk : (i < 196608) ? Wv : Wp;
    wf[i] = (f16)src[i & 65535];
}

// C[m,n] = sum_k A[m,k] * W[n,k]; A fp32 [M,256], W f16 [256,256] (row n = output ch)
// which: 0 -> qp [slice][t][e], 1 -> kp [slice][t][e]
// One block computes a full 64x256 tile (A loaded+converted ONCE).
// MFMA operands SWAPPED: mfma(Wfrag, Afrag) -> thread owns 4 consecutive n for one m
// => direct f16x4 (b64) stores, no LDS transpose needed.
__global__ __launch_bounds__(256)
void proj_kernel(const float* __restrict__ q, const float* __restrict__ kv,
                 const f16* __restrict__ wf, f16* __restrict__ ws)
{
    const int which = blockIdx.z;
    const float* A = (which == 0) ? q : kv;
    const f16* W = wf + which * 65536;
    f16* out = ws + (which == 0 ? QP_OFF : KP_OFF);

    const int tid = threadIdx.x;
    const int w = tid >> 6, l = tid & 63;
    const int lm = l & 15, g = l >> 4;
    const int m0 = blockIdx.x * 64;

    int arow = m0 + w * 16 + lm;
    const bool mok = arow < M_DIM;
    if (!mok) arow = M_DIM - 1;
    const float* Ab = A + (size_t)arow * C_DIM + g * 8;

    // preload & convert 8 A-fragments (K = 256) -- once per block now
    f16x8 af[8];
#pragma unroll
    for (int kk = 0; kk < 8; ++kk) {
        f32x4 a0 = *(const f32x4*)(Ab + kk * 32);
        f32x4 a1 = *(const f32x4*)(Ab + kk * 32 + 4);
#pragma unroll
        for (int j = 0; j < 4; ++j) { af[kk][j] = (f16)a0[j]; af[kk][4 + j] = (f16)a1[j]; }
    }

    f32x4 acc[16] = {};
#pragma unroll
    for (int nt = 0; nt < 16; ++nt) {
        const f16* Wb = W + (size_t)(nt * 16 + lm) * C_DIM + g * 8;
#pragma unroll
        for (int kk = 0; kk < 8; ++kk) {
            f16x8 bf = *(const f16x8*)(Wb + kk * 32);
            // swapped: D[row = n-index][col = m-index]
            acc[nt] = __builtin_amdgcn_mfma_f32_16x16x32_f16(bf, af[kk], acc[nt], 0, 0, 0);
        }
    }

    // thread's fixed output row m = arow; owns n = nt*16 + g*4 + {0..3}
    int b = arow / TJ;
    int rem = arow - b * TJ;
    int t = rem / J_DIM;
    int jj = rem - t * J_DIM;
    if (mok) {
#pragma unroll
        for (int nt = 0; nt < 16; ++nt) {
            int n0 = nt * 16 + g * 4;
            int h = n0 >> 5, e = n0 & 31;
            int sI = (b * H_DIM + h) * J_DIM + jj;
            f16x4 v;
#pragma unroll
            for (int r = 0; r < 4; ++r) v[r] = (f16)acc[nt][r];
            *(f16x4*)(out + (size_t)sI * (T_DIM * HD_DIM) + (size_t)t * HD_DIM + e) = v;
        }
    }
}

// V projection with t-major blocking per (b,j): coalesced vpT stores.
// vpT layout: [slice][e][t(256-padded)]; pad t>=243 written as true zeros.
__global__ __launch_bounds__(256)
void vproj_kernel(const float* __restrict__ kv, const f16* __restrict__ wv,
                  f16* __restrict__ vpt)
{
    __shared__ f16 Sv[64 * 72];

    const int bj = blockIdx.z;
    const int b = bj / J_DIM, j = bj - b * J_DIM;
    const int t0 = blockIdx.x * 64;
    const int n0 = blockIdx.y * 64;

    const int tid = threadIdx.x;
    const int w = tid >> 6, l = tid & 63;
    const int lm = l & 15, g = l >> 4;

    int t = t0 + w * 16 + lm;
    if (t > T_DIM - 1) t = T_DIM - 1;  // dup row, zeroed at store
    const float* Ab = kv + ((size_t)b * TJ + (size_t)t * J_DIM + j) * C_DIM + g * 8;

    f16x8 af[8];
#pragma unroll
    for (int kk = 0; kk < 8; ++kk) {
        f32x4 a0 = *(const f32x4*)(Ab + kk * 32);
        f32x4 a1 = *(const f32x4*)(Ab + kk * 32 + 4);
#pragma unroll
        for (int jj = 0; jj < 4; ++jj) { af[kk][jj] = (f16)a0[jj]; af[kk][4 + jj] = (f16)a1[jj]; }
    }

    f32x4 acc[4] = {};
#pragma unroll
    for (int nt = 0; nt < 4; ++nt) {
        const f16* Wb = wv + (size_t)(n0 + nt * 16 + lm) * C_DIM + g * 8;
#pragma unroll
        for (int kk = 0; kk < 8; ++kk) {
            f16x8 bf = *(const f16x8*)(Wb + kk * 32);
            acc[nt] = __builtin_amdgcn_mfma_f32_16x16x32_f16(af[kk], bf, acc[nt], 0, 0, 0);
        }
    }

    // transpose via LDS: Sv[n_local][t_local], row stride 72
    const int trow = w * 16 + g * 4;
#pragma unroll
    for (int nt = 0; nt < 4; ++nt) {
        int nl = nt * 16 + lm;
#pragma unroll
        for (int r = 0; r < 4; ++r)
            Sv[nl * 72 + trow + r] = (f16)acc[nt][r];
    }
    __syncthreads();

    // store: 4 threads per n-row, 16 t each -> contiguous 128B runs per (s,e)
    const int nl = tid >> 2, tp = tid & 3;
    const int n = n0 + nl;
    const int h = n >> 5, e = n & 31;
    const int s = (b * H_DIM + h) * J_DIM + j;
    const int tbase = t0 + tp * 16;

    f16x8 v0 = *(const f16x8*)&Sv[nl * 72 + tp * 16];
    f16x8 v1 = *(const f16x8*)&Sv[nl * 72 + tp * 16 + 8];
    if (tbase + 15 > T_DIM - 1) {
#pragma unroll
        for (int i = 0; i < 8; ++i) {
            if (tbase + i > T_DIM - 1) v0[i] = (f16)0;
            if (tbase + 8 + i > T_DIM - 1) v1[i] = (f16)0;
        }
    }
    f16* dst = vpt + (size_t)s * (HD_DIM * 256) + (size_t)e * 256 + tbase;
    *(f16x8*)dst = v0;
    *(f16x8*)(dst + 8) = v1;
}

// one block = one (slice, 64-row q-block). QK^T (SWAPPED operands) ->
// register softmax (2 shuffles) -> vectorized attn stores + PV
__global__ __launch_bounds__(256)
void attn_kernel(const f16* __restrict__ ws_qp, const f16* __restrict__ ws_kp,
                 const f16* __restrict__ ws_vpt, f16* __restrict__ ws_o,
                 float* __restrict__ attn_out)
{
    __shared__ f16 S[64 * 256];

    const int s = blockIdx.y;
    const int q0 = blockIdx.x * 64;
    const int tid = threadIdx.x;
    const int w = tid >> 6, l = tid & 63;
    const int lm = l & 15, g = l >> 4;
    const float scale = 0.17677669529663687f;  // 1/sqrt(32)

    const f16* qpS = ws_qp + (size_t)s * (T_DIM * HD_DIM);
    const f16* kpS = ws_kp + (size_t)s * (T_DIM * HD_DIM);

    int qrow = q0 + w * 16 + lm;
    const bool qok = qrow < T_DIM;
    if (!qok) qrow = T_DIM - 1;  // clamp: dup rows, guarded on store
    // Q as B-operand: lane lm holds q-row (q0 + w*16 + lm)
    f16x8 bq = *(const f16x8*)(qpS + qrow * HD_DIM + g * 8);

    // QK^T swapped: mfma(K, Q) -> D[row = k-index][col = q-row]
    // thread (lm,g) holds score[k = kt*16 + g*4 + r][q = q0 + w*16 + lm]
    float cv[16][4];
    f32x4 zero = {0.f, 0.f, 0.f, 0.f};
#pragma unroll
    for (int kt = 0; kt < 16; ++kt) {
        int krow = kt * 16 + lm;
        if (krow > T_DIM - 1) krow = T_DIM - 1;
        f16x8 ak = *(const f16x8*)(kpS + krow * HD_DIM + g * 8);
        f32x4 c = __builtin_amdgcn_mfma_f32_16x16x32_f16(ak, bq, zero, 0, 0, 0);
#pragma unroll
        for (int r = 0; r < 4; ++r) cv[kt][r] = c[r] * scale;
    }
    // mask pad k: k = 240 + g*4 + r >= 243  <=>  g*4 + r >= 3
#pragma unroll
    for (int r = 0; r < 4; ++r)
        if (g * 4 + r >= 3) cv[15][r] = -1e30f;

    // softmax over k for this thread's q-row: in-thread over 64 vals, then 2 shuffles
    float mx = -1e30f;
#pragma unroll
    for (int kt = 0; kt < 16; ++kt) {
        float a = fmaxf(fmaxf(cv[kt][0], cv[kt][1]), fmaxf(cv[kt][2], cv[kt][3]));
        mx = fmaxf(mx, a);
    }
    mx = fmaxf(mx, __shfl_xor(mx, 16));
    mx = fmaxf(mx, __shfl_xor(mx, 32));

    float s0 = 0.f, s1 = 0.f;
#pragma unroll
    for (int kt = 0; kt < 16; ++kt) {
        float p0 = __expf(cv[kt][0] - mx);
        float p1 = __expf(cv[kt][1] - mx);
        float p2 = __expf(cv[kt][2] - mx);
        float p3 = __expf(cv[kt][3] - mx);
        cv[kt][0] = p0; cv[kt][1] = p1; cv[kt][2] = p2; cv[kt][3] = p3;
        s0 += p0 + p1;
        s1 += p2 + p3;
    }
    float sum = s0 + s1;
    sum += __shfl_xor(sum, 16);
    sum += __shfl_xor(sum, 32);
    const float rinv = 1.0f / sum;

    // normalize + store: fp32 attn dwordx4 to global, f16x4 (b64) P to LDS
    float* drow = attn_out + (size_t)s * (T_DIM * T_DIM) + (size_t)qrow * T_DIM;
    const int qlocal = w * 16 + lm;
#pragma unroll
    for (int kt = 0; kt < 16; ++kt) {
        const int col0 = kt * 16 + g * 4;
        f16x4 pv4;
        f32x4a o4;
#pragma unroll
        for (int r = 0; r < 4; ++r) {
            float p = cv[kt][r] * rinv;
            o4[r] = p;
            pv4[r] = (f16)p;  // pad cols store exact 0
        }
        *(f16x4*)&S[qlocal * 256 + SWZ(qlocal, col0)] = pv4;
        if (qok) {
            if (col0 + 3 < T_DIM) {
                *(f32x4a*)(drow + col0) = o4;
            } else if (col0 < T_DIM) {  // kt==15, g==0: cols 240..242
                drow[col0] = o4[0];
                drow[col0 + 1] = o4[1];
                drow[col0 + 2] = o4[2];
            }
        }
    }
    __syncthreads();

    // PV: O[16 rows][32 e] per wave, V^T read direct from global (b128, L2-hot)
    const f16* vpS = ws_vpt + (size_t)s * (HD_DIM * 256);
    f32x4 o0 = {}, o1 = {};
    const int prow = w * 16 + lm;
#pragma unroll
    for (int kk = 0; kk < 8; ++kk) {
        f16x8 ap = *(const f16x8*)(&S[prow * 256 + SWZ(prow, kk * 32 + g * 8)]);
        f16x8 b0 = *(const f16x8*)(vpS + (size_t)(0 * 16 + lm) * 256 + kk * 32 + g * 8);
        f16x8 b1 = *(const f16x8*)(vpS + (size_t)(1 * 16 + lm) * 256 + kk * 32 + g * 8);
        o0 = __builtin_amdgcn_mfma_f32_16x16x32_f16(ap, b0, o0, 0, 0, 0);
        o1 = __builtin_amdgcn_mfma_f32_16x16x32_f16(ap, b1, o1, 0, 0, 0);
    }

    // store O to [m][256] f16 (input of final projection)
    int b = s / (H_DIM * J_DIM);
    int rem = s - b * (H_DIM * J_DIM);
    int h = rem / J_DIM;
    int jj = rem - h * J_DIM;
#pragma unroll
    for (int r = 0; r < 4; ++r) {
        int qr = q0 + w * 16 + g * 4 + r;
        if (qr >= T_DIM) continue;
        size_t m = (size_t)b * TJ + (size_t)qr * J_DIM + jj;
        ws_o[m * 256 + h * 32 + lm] = (f16)o0[r];
        ws_o[m * 256 + h * 32 + 16 + lm] = (f16)o1[r];
    }
}

// out[m,n] = sum_k O[m,k] * Wp[n,k] + bp[n], fp32 out
// One block computes 64x256 (O loaded once); swapped MFMA -> dwordx4 stores.
__global__ __launch_bounds__(256)
void outproj_kernel(const f16* __restrict__ ws_o, const f16* __restrict__ wpf,
                    const float* __restrict__ bp, float* __restrict__ out)
{
    const int tid = threadIdx.x;
    const int w = tid >> 6, l = tid & 63;
    const int lm = l & 15, g = l >> 4;
    const int m0 = blockIdx.x * 64;

    int m = m0 + w * 16 + lm;
    const bool mok = m < M_DIM;
    if (!mok) m = M_DIM - 1;
    const f16* Ab = ws_o + (size_t)m * C_DIM + g * 8;
    f16x8 af[8];
#pragma unroll
    for (int kk = 0; kk < 8; ++kk) af[kk] = *(const f16x8*)(Ab + kk * 32);

    f32x4 acc[16] = {};
#pragma unroll
    for (int nt = 0; nt < 16; ++nt) {
        const f16* Wb = wpf + (size_t)(nt * 16 + lm) * C_DIM + g * 8;
#pragma unroll
        for (int kk = 0; kk < 8; ++kk) {
            f16x8 bf = *(const f16x8*)(Wb + kk * 32);
            acc[nt] = __builtin_amdgcn_mfma_f32_16x16x32_f16(bf, af[kk], acc[nt], 0, 0, 0);
        }
    }

    if (mok) {
#pragma unroll
        for (int nt = 0; nt < 16; ++nt) {
            int n0 = nt * 16 + g * 4;
            f32x4a bv = *(const f32x4a*)(bp + n0);
            f32x4a o;
#pragma unroll
            for (int r = 0; r < 4; ++r) o[r] = acc[nt][r] + bv[r];
            *(f32x4a*)(out + (size_t)m * C_DIM + n0) = o;
        }
    }
}

extern "C" void kernel_launch(void* const* d_in, const int* in_sizes, int n_in,
                              void* d_out, int out_size, void* d_ws, size_t ws_size,
                              hipStream_t stream)
{
    const float* q  = (const float*)d_in[0];
    const float* kv = (const float*)d_in[1];
    const float* Wq = (const float*)d_in[2];
    const float* Wk = (const float*)d_in[3];
    const float* Wv = (const float*)d_in[4];
    const float* Wp = (const float*)d_in[5];
    const float* bp = (const float*)d_in[6];
    float* attn_out = (float*)d_out;
    float* out = attn_out + ATTN_SZ;
    f16* ws = (f16*)d_ws;

    wconv_kernel<<<dim3(1024), dim3(256), 0, stream>>>(Wq, Wk, Wv, Wp, ws + WF_OFF);

    dim3 gp((M_DIM + 63) / 64, 1, 2);
    proj_kernel<<<gp, dim3(256), 0, stream>>>(q, kv, ws + WF_OFF, ws);

    dim3 gv(4, 4, B_DIM * J_DIM);
    vproj_kernel<<<gv, dim3(256), 0, stream>>>(kv, ws + WF_OFF + 2 * 65536, ws + VPT_OFF);

    dim3 ga(4, NSLICE);
    attn_kernel<<<ga, dim3(256), 0, stream>>>(ws + QP_OFF, ws + KP_OFF, ws + VPT_OFF,
                                              ws + O_OFF, attn_out);

    dim3 go((M_DIM + 63) / 64, 1);
    outproj_kernel<<<go, dim3(256), 0, stream>>>(ws + O_OFF, ws + WF_OFF + 3 * 65536, bp, out);
}

// Round 3
// 551.562 us; speedup vs baseline: 1.0909x; 1.0854x over previous
//
#include <hip/hip_runtime.h>

typedef _Float16 f16;
typedef _Float16 f16x8 __attribute__((ext_vector_type(8)));
typedef _Float16 f16x4 __attribute__((ext_vector_type(4)));
typedef float f32x4 __attribute__((ext_vector_type(4)));
typedef float f32x4a __attribute__((ext_vector_type(4), aligned(4)));

#define B_DIM 16
#define T_DIM 243
#define J_DIM 17
#define C_DIM 256
#define H_DIM 8
#define HD_DIM 32
#define M_DIM (B_DIM * T_DIM * J_DIM)   // 66096
#define NSLICE (B_DIM * H_DIM * J_DIM)  // 2176
#define TJ (T_DIM * J_DIM)              // 4131

// workspace layout, in f16 units
#define QP_OFF 0ull
#define KP_OFF ((unsigned long long)NSLICE * T_DIM * HD_DIM)          // 16,920,576
#define VPT_OFF (2ull * KP_OFF)                                        // 33,841,152
#define O_OFF (VPT_OFF + (unsigned long long)NSLICE * HD_DIM * 256)    // + 17,825,792
#define WF_OFF (O_OFF + (unsigned long long)M_DIM * C_DIM)             // + 16,920,576
#define ATTN_SZ ((unsigned long long)NSLICE * T_DIM * T_DIM)           // 128,490,624

// XOR swizzle for the P buffer: keeps aligned 4/8-f16 blocks contiguous
#define SWZ(row, col) ((col) ^ (((row) & 7) << 3))

__global__ __launch_bounds__(256)
void wconv_kernel(const float* __restrict__ Wq, const float* __restrict__ Wk,
                  const float* __restrict__ Wv, const float* __restrict__ Wp,
                  f16* __restrict__ wf)
{
    int i = blockIdx.x * 256 + threadIdx.x;  // 0 .. 4*65536-1
    const float* src = (i < 65536) ? Wq : (i < 131072) ? Wk : (i < 196608) ? Wv : Wp;
    wf[i] = (f16)src[i & 65535];
}

// C[m,n] = sum_k A[m,k] * W[n,k]; A fp32 [M,256], W f16 [256,256] (row n = output ch)
// which: 0 -> qp [slice][t][e] (PRE-SCALED by 1/sqrt(hd)), 1 -> kp [slice][t][e]
__global__ __launch_bounds__(256)
void proj_kernel(const float* __restrict__ q, const float* __restrict__ kv,
                 const f16* __restrict__ wf, f16* __restrict__ ws)
{
    const int which = blockIdx.z;
    const float* A = (which == 0) ? q : kv;
    const f16* W = wf + which * 65536;
    f16* out = ws + (which == 0 ? QP_OFF : KP_OFF);
    const float osc = (which == 0) ? 0.17677669529663687f : 1.0f;  // fold 1/sqrt(32) into Q

    const int tid = threadIdx.x;
    const int w = tid >> 6, l = tid & 63;
    const int lm = l & 15, g = l >> 4;
    const int m0 = blockIdx.x * 64;

    int arow = m0 + w * 16 + lm;
    const bool mok = arow < M_DIM;
    if (!mok) arow = M_DIM - 1;
    const float* Ab = A + (size_t)arow * C_DIM + g * 8;

    // preload & convert 8 A-fragments (K = 256) -- once per block
    f16x8 af[8];
#pragma unroll
    for (int kk = 0; kk < 8; ++kk) {
        f32x4 a0 = *(const f32x4*)(Ab + kk * 32);
        f32x4 a1 = *(const f32x4*)(Ab + kk * 32 + 4);
#pragma unroll
        for (int j = 0; j < 4; ++j) { af[kk][j] = (f16)a0[j]; af[kk][4 + j] = (f16)a1[j]; }
    }

    f32x4 acc[16] = {};
#pragma unroll
    for (int nt = 0; nt < 16; ++nt) {
        const f16* Wb = W + (size_t)(nt * 16 + lm) * C_DIM + g * 8;
#pragma unroll
        for (int kk = 0; kk < 8; ++kk) {
            f16x8 bf = *(const f16x8*)(Wb + kk * 32);
            // swapped: D[row = n-index][col = m-index]
            acc[nt] = __builtin_amdgcn_mfma_f32_16x16x32_f16(bf, af[kk], acc[nt], 0, 0, 0);
        }
    }

    // thread's fixed output row m = arow; owns n = nt*16 + g*4 + {0..3}
    int b = arow / TJ;
    int rem = arow - b * TJ;
    int t = rem / J_DIM;
    int jj = rem - t * J_DIM;
    if (mok) {
#pragma unroll
        for (int nt = 0; nt < 16; ++nt) {
            int n0 = nt * 16 + g * 4;
            int h = n0 >> 5, e = n0 & 31;
            int sI = (b * H_DIM + h) * J_DIM + jj;
            f16x4 v;
#pragma unroll
            for (int r = 0; r < 4; ++r) v[r] = (f16)(acc[nt][r] * osc);
            *(f16x4*)(out + (size_t)sI * (T_DIM * HD_DIM) + (size_t)t * HD_DIM + e) = v;
        }
    }
}

// V projection with t-major blocking per (b,j): coalesced vpT stores.
// vpT layout: [slice][e][t(256-padded)]; pad t>=243 written as true zeros.
__global__ __launch_bounds__(256)
void vproj_kernel(const float* __restrict__ kv, const f16* __restrict__ wv,
                  f16* __restrict__ vpt)
{
    __shared__ f16 Sv[64 * 72];

    const int bj = blockIdx.z;
    const int b = bj / J_DIM, j = bj - b * J_DIM;
    const int t0 = blockIdx.x * 64;
    const int n0 = blockIdx.y * 64;

    const int tid = threadIdx.x;
    const int w = tid >> 6, l = tid & 63;
    const int lm = l & 15, g = l >> 4;

    int t = t0 + w * 16 + lm;
    if (t > T_DIM - 1) t = T_DIM - 1;  // dup row, zeroed at store
    const float* Ab = kv + ((size_t)b * TJ + (size_t)t * J_DIM + j) * C_DIM + g * 8;

    f16x8 af[8];
#pragma unroll
    for (int kk = 0; kk < 8; ++kk) {
        f32x4 a0 = *(const f32x4*)(Ab + kk * 32);
        f32x4 a1 = *(const f32x4*)(Ab + kk * 32 + 4);
#pragma unroll
        for (int jj = 0; jj < 4; ++jj) { af[kk][jj] = (f16)a0[jj]; af[kk][4 + jj] = (f16)a1[jj]; }
    }

    f32x4 acc[4] = {};
#pragma unroll
    for (int nt = 0; nt < 4; ++nt) {
        const f16* Wb = wv + (size_t)(n0 + nt * 16 + lm) * C_DIM + g * 8;
#pragma unroll
        for (int kk = 0; kk < 8; ++kk) {
            f16x8 bf = *(const f16x8*)(Wb + kk * 32);
            acc[nt] = __builtin_amdgcn_mfma_f32_16x16x32_f16(af[kk], bf, acc[nt], 0, 0, 0);
        }
    }

    // transpose via LDS: Sv[n_local][t_local], row stride 72
    const int trow = w * 16 + g * 4;
#pragma unroll
    for (int nt = 0; nt < 4; ++nt) {
        int nl = nt * 16 + lm;
#pragma unroll
        for (int r = 0; r < 4; ++r)
            Sv[nl * 72 + trow + r] = (f16)acc[nt][r];
    }
    __syncthreads();

    // store: 4 threads per n-row, 16 t each -> contiguous 128B runs per (s,e)
    const int nl = tid >> 2, tp = tid & 3;
    const int n = n0 + nl;
    const int h = n >> 5, e = n & 31;
    const int s = (b * H_DIM + h) * J_DIM + j;
    const int tbase = t0 + tp * 16;

    f16x8 v0 = *(const f16x8*)&Sv[nl * 72 + tp * 16];
    f16x8 v1 = *(const f16x8*)&Sv[nl * 72 + tp * 16 + 8];
    if (tbase + 15 > T_DIM - 1) {
#pragma unroll
        for (int i = 0; i < 8; ++i) {
            if (tbase + i > T_DIM - 1) v0[i] = (f16)0;
            if (tbase + 8 + i > T_DIM - 1) v1[i] = (f16)0;
        }
    }
    f16* dst = vpt + (size_t)s * (HD_DIM * 256) + (size_t)e * 256 + tbase;
    *(f16x8*)dst = v0;
    *(f16x8*)(dst + 8) = v1;
}

// one block = one (slice, 64-row q-block).
// K staged in LDS (reusing the P buffer) -> QK^T (swapped) -> register softmax
// -> P to LDS -> contiguous attn_out row-stores from LDS + PV.
// K-row layout: 64 B/row, block gp at byte t*64 + 16*((gp + (t>>3)) & 3)
//   -> per quarter-wave the 16 b128 accesses hit 16 distinct 16-B slots (2/bank, free).
__global__ __launch_bounds__(256)
void attn_kernel(const f16* __restrict__ ws_qp, const f16* __restrict__ ws_kp,
                 const f16* __restrict__ ws_vpt, f16* __restrict__ ws_o,
                 float* __restrict__ attn_out)
{
    __shared__ f16 S[64 * 256];  // 32 KB: K-stage (first 16 KB) then P (full)

    const int s = blockIdx.y;
    const int q0 = blockIdx.x * 64;
    const int tid = threadIdx.x;
    const int w = tid >> 6, l = tid & 63;
    const int lm = l & 15, g = l >> 4;

    const f16* qpS = ws_qp + (size_t)s * (T_DIM * HD_DIM);
    const f16* kpS = ws_kp + (size_t)s * (T_DIM * HD_DIM);

    // ---- stage K into S (rows 0..255, 64 B each; rotation stays inside the row)
    {
        const int t = tid;
        char* drow = (char*)S + t * 64;
        const int rot = t >> 3;
        if (t < T_DIM) {
            const f16* src = kpS + t * HD_DIM;
#pragma unroll
            for (int gp = 0; gp < 4; ++gp) {
                f16x8 v = *(const f16x8*)(src + gp * 8);
                *(f16x8*)(drow + 16 * ((gp + rot) & 3)) = v;
            }
        } else {  // zero pad rows 243..255
            f16x8 z = {};
#pragma unroll
            for (int gp = 0; gp < 4; ++gp)
                *(f16x8*)(drow + 16 * ((gp + rot) & 3)) = z;
        }
    }

    int qrow = q0 + w * 16 + lm;
    const bool qok_load = qrow < T_DIM;
    if (!qok_load) qrow = T_DIM - 1;  // dup row; masked on store
    f16x8 bq = *(const f16x8*)(qpS + qrow * HD_DIM + g * 8);  // pre-scaled Q

    __syncthreads();

    // ---- QK^T swapped: mfma(K, Q) -> D[k][q]; thread owns k = kt*16+g*4+r, q-row = lm
    // K read: row = kt*16+lm; rot = (row>>3)&3 = ((lm>>3) + 2*kt) & 3
    const char* kb = (const char*)S + lm * 64;
    const int rb = g + (lm >> 3);
    const int off_e = 16 * (rb & 3);        // kt even
    const int off_o = 16 * ((rb + 2) & 3);  // kt odd
    float cv[16][4];
    f32x4 zero = {0.f, 0.f, 0.f, 0.f};
#pragma unroll
    for (int kt = 0; kt < 16; ++kt) {
        f16x8 ak = *(const f16x8*)(kb + kt * 1024 + ((kt & 1) ? off_o : off_e));
        f32x4 c = __builtin_amdgcn_mfma_f32_16x16x32_f16(ak, bq, zero, 0, 0, 0);
#pragma unroll
        for (int r = 0; r < 4; ++r) cv[kt][r] = c[r];
    }
    // mask pad k: k = 240 + g*4 + r >= 243  <=>  g*4 + r >= 3
#pragma unroll
    for (int r = 0; r < 4; ++r)
        if (g * 4 + r >= 3) cv[15][r] = -1e30f;

    // softmax over k for this thread's q-row: in-thread over 64 vals, then 2 shuffles
    float mx = -1e30f;
#pragma unroll
    for (int kt = 0; kt < 16; ++kt) {
        float a = fmaxf(fmaxf(cv[kt][0], cv[kt][1]), fmaxf(cv[kt][2], cv[kt][3]));
        mx = fmaxf(mx, a);
    }
    mx = fmaxf(mx, __shfl_xor(mx, 16));
    mx = fmaxf(mx, __shfl_xor(mx, 32));

    float s0 = 0.f, s1 = 0.f;
#pragma unroll
    for (int kt = 0; kt < 16; ++kt) {
        float p0 = __expf(cv[kt][0] - mx);
        float p1 = __expf(cv[kt][1] - mx);
        float p2 = __expf(cv[kt][2] - mx);
        float p3 = __expf(cv[kt][3] - mx);
        cv[kt][0] = p0; cv[kt][1] = p1; cv[kt][2] = p2; cv[kt][3] = p3;
        s0 += p0 + p1;
        s1 += p2 + p3;
    }
    float sum = s0 + s1;
    sum += __shfl_xor(sum, 16);
    sum += __shfl_xor(sum, 32);
    const float rinv = 1.0f / sum;

    __syncthreads();  // all waves done reading K before P overwrites S

    // ---- normalized P (f16) to LDS; wave w writes exactly rows [w*16, w*16+16)
    const int qlocal = w * 16 + lm;
#pragma unroll
    for (int kt = 0; kt < 16; ++kt) {
        const int col0 = kt * 16 + g * 4;
        f16x4 pv4;
#pragma unroll
        for (int r = 0; r < 4; ++r) pv4[r] = (f16)(cv[kt][r] * rinv);
        *(f16x4*)&S[qlocal * 256 + SWZ(qlocal, col0)] = pv4;
    }
    // no barrier needed: each wave reads back only its own 16 rows below

    // ---- attn_out: contiguous 972-B row stores from S (lane l -> cols 4l..4l+3)
    float* dst = attn_out + (size_t)s * (T_DIM * T_DIM);
#pragma unroll
    for (int rr = 0; rr < 16; ++rr) {
        const int row = w * 16 + rr;
        const int qr = q0 + row;
        if (qr < T_DIM) {  // wave-uniform
            const int col = l * 4;
            f16x4 pv = *(const f16x4*)&S[row * 256 + SWZ(row, col)];
            float* p = dst + (size_t)qr * T_DIM + col;
            if (col + 3 < T_DIM) {          // lanes 0..59
                f32x4a o4;
#pragma unroll
                for (int r = 0; r < 4; ++r) o4[r] = (float)pv[r];
                *(f32x4a*)p = o4;
            } else if (col < T_DIM) {       // lane 60: cols 240..242
                p[0] = (float)pv[0]; p[1] = (float)pv[1]; p[2] = (float)pv[2];
            }
        }
    }

    // ---- PV: O[16 rows][32 e] per wave, V^T read direct from global (b128, L2-hot)
    const f16* vpS = ws_vpt + (size_t)s * (HD_DIM * 256);
    f32x4 o0 = {}, o1 = {};
    const int prow = w * 16 + lm;
#pragma unroll
    for (int kk = 0; kk < 8; ++kk) {
        f16x8 ap = *(const f16x8*)(&S[prow * 256 + SWZ(prow, kk * 32 + g * 8)]);
        f16x8 b0 = *(const f16x8*)(vpS + (size_t)(0 * 16 + lm) * 256 + kk * 32 + g * 8);
        f16x8 b1 = *(const f16x8*)(vpS + (size_t)(1 * 16 + lm) * 256 + kk * 32 + g * 8);
        o0 = __builtin_amdgcn_mfma_f32_16x16x32_f16(ap, b0, o0, 0, 0, 0);
        o1 = __builtin_amdgcn_mfma_f32_16x16x32_f16(ap, b1, o1, 0, 0, 0);
    }

    // store O to [m][256] f16 (input of final projection)
    int b = s / (H_DIM * J_DIM);
    int rem = s - b * (H_DIM * J_DIM);
    int h = rem / J_DIM;
    int jj = rem - h * J_DIM;
#pragma unroll
    for (int r = 0; r < 4; ++r) {
        int qr = q0 + w * 16 + g * 4 + r;
        if (qr >= T_DIM) continue;
        size_t m = (size_t)b * TJ + (size_t)qr * J_DIM + jj;
        ws_o[m * 256 + h * 32 + lm] = (f16)o0[r];
        ws_o[m * 256 + h * 32 + 16 + lm] = (f16)o1[r];
    }
}

// out[m,n] = sum_k O[m,k] * Wp[n,k] + bp[n], fp32 out
__global__ __launch_bounds__(256)
void outproj_kernel(const f16* __restrict__ ws_o, const f16* __restrict__ wpf,
                    const float* __restrict__ bp, float* __restrict__ out)
{
    const int tid = threadIdx.x;
    const int w = tid >> 6, l = tid & 63;
    const int lm = l & 15, g = l >> 4;
    const int m0 = blockIdx.x * 64;

    int m = m0 + w * 16 + lm;
    const bool mok = m < M_DIM;
    if (!mok) m = M_DIM - 1;
    const f16* Ab = ws_o + (size_t)m * C_DIM + g * 8;
    f16x8 af[8];
#pragma unroll
    for (int kk = 0; kk < 8; ++kk) af[kk] = *(const f16x8*)(Ab + kk * 32);

    f32x4 acc[16] = {};
#pragma unroll
    for (int nt = 0; nt < 16; ++nt) {
        const f16* Wb = wpf + (size_t)(nt * 16 + lm) * C_DIM + g * 8;
#pragma unroll
        for (int kk = 0; kk < 8; ++kk) {
            f16x8 bf = *(const f16x8*)(Wb + kk * 32);
            acc[nt] = __builtin_amdgcn_mfma_f32_16x16x32_f16(bf, af[kk], acc[nt], 0, 0, 0);
        }
    }

    if (mok) {
#pragma unroll
        for (int nt = 0; nt < 16; ++nt) {
            int n0 = nt * 16 + g * 4;
            f32x4a bv = *(const f32x4a*)(bp + n0);
            f32x4a o;
#pragma unroll
            for (int r = 0; r < 4; ++r) o[r] = acc[nt][r] + bv[r];
            *(f32x4a*)(out + (size_t)m * C_DIM + n0) = o;
        }
    }
}

extern "C" void kernel_launch(void* const* d_in, const int* in_sizes, int n_in,
                              void* d_out, int out_size, void* d_ws, size_t ws_size,
                              hipStream_t stream)
{
    const float* q  = (const float*)d_in[0];
    const float* kv = (const float*)d_in[1];
    const float* Wq = (const float*)d_in[2];
    const float* Wk = (const float*)d_in[3];
    const float* Wv = (const float*)d_in[4];
    const float* Wp = (const float*)d_in[5];
    const float* bp = (const float*)d_in[6];
    float* attn_out = (float*)d_out;
    float* out = attn_out + ATTN_SZ;
    f16* ws = (f16*)d_ws;

    wconv_kernel<<<dim3(1024), dim3(256), 0, stream>>>(Wq, Wk, Wv, Wp, ws + WF_OFF);

    dim3 gp((M_DIM + 63) / 64, 1, 2);
    proj_kernel<<<gp, dim3(256), 0, stream>>>(q, kv, ws + WF_OFF, ws);

    dim3 gv(4, 4, B_DIM * J_DIM);
    vproj_kernel<<<gv, dim3(256), 0, stream>>>(kv, ws + WF_OFF + 2 * 65536, ws + VPT_OFF);

    dim3 ga(4, NSLICE);
    attn_kernel<<<ga, dim3(256), 0, stream>>>(ws + QP_OFF, ws + KP_OFF, ws + VPT_OFF,
                                              ws + O_OFF, attn_out);

    dim3 go((M_DIM + 63) / 64, 1);
    outproj_kernel<<<go, dim3(256), 0, stream>>>(ws + O_OFF, ws + WF_OFF + 3 * 65536, bp, out);
}

// Round 4
// 547.895 us; speedup vs baseline: 1.0982x; 1.0067x over previous
//
#include <hip/hip_runtime.h>

typedef _Float16 f16;
typedef _Float16 f16x8 __attribute__((ext_vector_type(8)));
typedef _Float16 f16x4 __attribute__((ext_vector_type(4)));
typedef float f32x4 __attribute__((ext_vector_type(4)));
typedef float f32x4a __attribute__((ext_vector_type(4), aligned(4)));

#define B_DIM 16
#define T_DIM 243
#define J_DIM 17
#define C_DIM 256
#define H_DIM 8
#define HD_DIM 32
#define M_DIM (B_DIM * T_DIM * J_DIM)   // 66096
#define NSLICE (B_DIM * H_DIM * J_DIM)  // 2176
#define TJ (T_DIM * J_DIM)              // 4131

// workspace layout, in f16 units
#define QP_OFF 0ull
#define KP_OFF ((unsigned long long)NSLICE * T_DIM * HD_DIM)          // 16,920,576
#define VPT_OFF (2ull * KP_OFF)                                        // 33,841,152
#define O_OFF (VPT_OFF + (unsigned long long)NSLICE * HD_DIM * 256)    // + 17,825,792
#define WF_OFF (O_OFF + (unsigned long long)M_DIM * C_DIM)             // + 16,920,576
#define ATTN_SZ ((unsigned long long)NSLICE * T_DIM * T_DIM)           // 128,490,624

// XOR swizzle for the P buffer: keeps aligned 4/8-f16 blocks contiguous
#define SWZ(row, col) ((col) ^ (((row) & 7) << 3))

__global__ __launch_bounds__(256)
void wconv_kernel(const float* __restrict__ Wq, const float* __restrict__ Wk,
                  const float* __restrict__ Wv, const float* __restrict__ Wp,
                  f16* __restrict__ wf)
{
    int i = blockIdx.x * 256 + threadIdx.x;  // 0 .. 4*65536-1
    const float* src = (i < 65536) ? Wq : (i < 131072) ? Wk : (i < 196608) ? Wv : Wp;
    wf[i] = (f16)src[i & 65535];
}

// Q projection only: qp[slice][t][e], PRE-SCALED by 1/sqrt(hd).
// One block = 64 m-rows x 256 n; A loaded+converted once; swapped MFMA -> f16x4 stores.
__global__ __launch_bounds__(256)
void proj_kernel(const float* __restrict__ q, const f16* __restrict__ wq,
                 f16* __restrict__ qp)
{
    const float osc = 0.17677669529663687f;  // 1/sqrt(32)

    const int tid = threadIdx.x;
    const int w = tid >> 6, l = tid & 63;
    const int lm = l & 15, g = l >> 4;
    const int m0 = blockIdx.x * 64;

    int arow = m0 + w * 16 + lm;
    const bool mok = arow < M_DIM;
    if (!mok) arow = M_DIM - 1;
    const float* Ab = q + (size_t)arow * C_DIM + g * 8;

    f16x8 af[8];
#pragma unroll
    for (int kk = 0; kk < 8; ++kk) {
        f32x4 a0 = *(const f32x4*)(Ab + kk * 32);
        f32x4 a1 = *(const f32x4*)(Ab + kk * 32 + 4);
#pragma unroll
        for (int j = 0; j < 4; ++j) { af[kk][j] = (f16)a0[j]; af[kk][4 + j] = (f16)a1[j]; }
    }

    f32x4 acc[16] = {};
#pragma unroll
    for (int nt = 0; nt < 16; ++nt) {
        const f16* Wb = wq + (size_t)(nt * 16 + lm) * C_DIM + g * 8;
#pragma unroll
        for (int kk = 0; kk < 8; ++kk) {
            f16x8 bf = *(const f16x8*)(Wb + kk * 32);
            acc[nt] = __builtin_amdgcn_mfma_f32_16x16x32_f16(bf, af[kk], acc[nt], 0, 0, 0);
        }
    }

    int b = arow / TJ;
    int rem = arow - b * TJ;
    int t = rem / J_DIM;
    int jj = rem - t * J_DIM;
    if (mok) {
#pragma unroll
        for (int nt = 0; nt < 16; ++nt) {
            int n0 = nt * 16 + g * 4;
            int h = n0 >> 5, e = n0 & 31;
            int sI = (b * H_DIM + h) * J_DIM + jj;
            f16x4 v;
#pragma unroll
            for (int r = 0; r < 4; ++r) v[r] = (f16)(acc[nt][r] * osc);
            *(f16x4*)(qp + (size_t)sI * (T_DIM * HD_DIM) + (size_t)t * HD_DIM + e) = v;
        }
    }
}

// Merged K+V projection: reads kv ONCE per row (A-fragments shared).
// Per block: (b,j) slice-group, 64 t-rows, full n=256.
//   K: swapped MFMA -> direct f16x4 stores to kp[slice][t][e].
//   V: non-swapped MFMA in 4 n-chunks of 64, LDS-transposed -> vpt[slice][e][t(256pad)].
__global__ __launch_bounds__(256)
void kvproj_kernel(const float* __restrict__ kv, const f16* __restrict__ wf,
                   f16* __restrict__ kp, f16* __restrict__ vpt)
{
    __shared__ f16 Sv[64 * 72];
    const f16* Wk = wf + 65536;
    const f16* Wv = wf + 2 * 65536;

    const int bj = blockIdx.y;
    const int b = bj / J_DIM, j = bj - b * J_DIM;
    const int t0 = blockIdx.x * 64;

    const int tid = threadIdx.x;
    const int w = tid >> 6, l = tid & 63;
    const int lm = l & 15, g = l >> 4;

    const int traw = t0 + w * 16 + lm;
    const bool tok = traw < T_DIM;
    const int t = tok ? traw : T_DIM - 1;  // dup row; K store guarded, V zeroed at store
    const float* Ab = kv + ((size_t)b * TJ + (size_t)t * J_DIM + j) * C_DIM + g * 8;

    // load + convert A-fragments ONCE (shared by K and V)
    f16x8 af[8];
#pragma unroll
    for (int kk = 0; kk < 8; ++kk) {
        f32x4 a0 = *(const f32x4*)(Ab + kk * 32);
        f32x4 a1 = *(const f32x4*)(Ab + kk * 32 + 4);
#pragma unroll
        for (int jj2 = 0; jj2 < 4; ++jj2) { af[kk][jj2] = (f16)a0[jj2]; af[kk][4 + jj2] = (f16)a1[jj2]; }
    }

    // ---- K: swapped MFMA, thread owns (t fixed, n = nt*16 + g*4 + 0..3)
    {
        f32x4 kacc[16] = {};
#pragma unroll
        for (int nt = 0; nt < 16; ++nt) {
            const f16* Wb = Wk + (size_t)(nt * 16 + lm) * C_DIM + g * 8;
#pragma unroll
            for (int kk = 0; kk < 8; ++kk) {
                f16x8 bf = *(const f16x8*)(Wb + kk * 32);
                kacc[nt] = __builtin_amdgcn_mfma_f32_16x16x32_f16(bf, af[kk], kacc[nt], 0, 0, 0);
            }
        }
        if (tok) {
#pragma unroll
            for (int nt = 0; nt < 16; ++nt) {
                int n0 = nt * 16 + g * 4;
                int h = n0 >> 5, e = n0 & 31;
                int sI = (b * H_DIM + h) * J_DIM + j;
                f16x4 v;
#pragma unroll
                for (int r = 0; r < 4; ++r) v[r] = (f16)kacc[nt][r];
                *(f16x4*)(kp + (size_t)sI * (T_DIM * HD_DIM) + (size_t)t * HD_DIM + e) = v;
            }
        }
    }

    // ---- V: 4 n-chunks of 64; non-swapped MFMA -> Sv transpose -> coalesced stores
    const int trowl = w * 16 + g * 4;
    const int nl2 = tid >> 2, tp = tid & 3;
    const int tbase = t0 + tp * 16;
#pragma unroll 1
    for (int nc = 0; nc < 4; ++nc) {
        f32x4 vacc[4] = {};
#pragma unroll
        for (int nt = 0; nt < 4; ++nt) {
            const f16* Wb = Wv + (size_t)(nc * 64 + nt * 16 + lm) * C_DIM + g * 8;
#pragma unroll
            for (int kk = 0; kk < 8; ++kk) {
                f16x8 bf = *(const f16x8*)(Wb + kk * 32);
                vacc[nt] = __builtin_amdgcn_mfma_f32_16x16x32_f16(af[kk], bf, vacc[nt], 0, 0, 0);
            }
        }
        __syncthreads();  // previous chunk's Sv reads complete
#pragma unroll
        for (int nt = 0; nt < 4; ++nt) {
            int nl = nt * 16 + lm;
#pragma unroll
            for (int r = 0; r < 4; ++r)
                Sv[nl * 72 + trowl + r] = (f16)vacc[nt][r];
        }
        __syncthreads();

        const int n = nc * 64 + nl2;
        const int h = n >> 5, e = n & 31;
        const int sI = (b * H_DIM + h) * J_DIM + j;

        f16x8 v0 = *(const f16x8*)&Sv[nl2 * 72 + tp * 16];
        f16x8 v1 = *(const f16x8*)&Sv[nl2 * 72 + tp * 16 + 8];
        if (tbase + 15 > T_DIM - 1) {
#pragma unroll
            for (int i = 0; i < 8; ++i) {
                if (tbase + i > T_DIM - 1) v0[i] = (f16)0;
                if (tbase + 8 + i > T_DIM - 1) v1[i] = (f16)0;
            }
        }
        f16* dst = vpt + (size_t)sI * (HD_DIM * 256) + (size_t)e * 256 + tbase;
        *(f16x8*)dst = v0;
        *(f16x8*)(dst + 8) = v1;
    }
}

// one block = one (slice, 64-row q-block).
// K staged in LDS (reusing the P buffer) -> QK^T (swapped) -> register softmax
// -> P to LDS -> contiguous attn_out row-stores from LDS + PV.
__global__ __launch_bounds__(256)
void attn_kernel(const f16* __restrict__ ws_qp, const f16* __restrict__ ws_kp,
                 const f16* __restrict__ ws_vpt, f16* __restrict__ ws_o,
                 float* __restrict__ attn_out)
{
    __shared__ f16 S[64 * 256];  // 32 KB: K-stage (first 16 KB) then P (full)

    const int s = blockIdx.y;
    const int q0 = blockIdx.x * 64;
    const int tid = threadIdx.x;
    const int w = tid >> 6, l = tid & 63;
    const int lm = l & 15, g = l >> 4;

    const f16* qpS = ws_qp + (size_t)s * (T_DIM * HD_DIM);
    const f16* kpS = ws_kp + (size_t)s * (T_DIM * HD_DIM);

    // ---- stage K into S (rows 0..255, 64 B each; rotation stays inside the row)
    {
        const int t = tid;
        char* drow = (char*)S + t * 64;
        const int rot = t >> 3;
        if (t < T_DIM) {
            const f16* src = kpS + t * HD_DIM;
#pragma unroll
            for (int gp = 0; gp < 4; ++gp) {
                f16x8 v = *(const f16x8*)(src + gp * 8);
                *(f16x8*)(drow + 16 * ((gp + rot) & 3)) = v;
            }
        } else {  // zero pad rows 243..255
            f16x8 z = {};
#pragma unroll
            for (int gp = 0; gp < 4; ++gp)
                *(f16x8*)(drow + 16 * ((gp + rot) & 3)) = z;
        }
    }

    int qrow = q0 + w * 16 + lm;
    const bool qok_load = qrow < T_DIM;
    if (!qok_load) qrow = T_DIM - 1;  // dup row; masked on store
    f16x8 bq = *(const f16x8*)(qpS + qrow * HD_DIM + g * 8);  // pre-scaled Q

    __syncthreads();

    // ---- QK^T swapped: mfma(K, Q) -> D[k][q]; thread owns k = kt*16+g*4+r, q-row = lm
    const char* kb = (const char*)S + lm * 64;
    const int rb = g + (lm >> 3);
    const int off_e = 16 * (rb & 3);        // kt even
    const int off_o = 16 * ((rb + 2) & 3);  // kt odd
    float cv[16][4];
    f32x4 zero = {0.f, 0.f, 0.f, 0.f};
#pragma unroll
    for (int kt = 0; kt < 16; ++kt) {
        f16x8 ak = *(const f16x8*)(kb + kt * 1024 + ((kt & 1) ? off_o : off_e));
        f32x4 c = __builtin_amdgcn_mfma_f32_16x16x32_f16(ak, bq, zero, 0, 0, 0);
#pragma unroll
        for (int r = 0; r < 4; ++r) cv[kt][r] = c[r];
    }
    // mask pad k: k = 240 + g*4 + r >= 243  <=>  g*4 + r >= 3
#pragma unroll
    for (int r = 0; r < 4; ++r)
        if (g * 4 + r >= 3) cv[15][r] = -1e30f;

    // softmax over k for this thread's q-row: in-thread over 64 vals, then 2 shuffles
    float mx = -1e30f;
#pragma unroll
    for (int kt = 0; kt < 16; ++kt) {
        float a = fmaxf(fmaxf(cv[kt][0], cv[kt][1]), fmaxf(cv[kt][2], cv[kt][3]));
        mx = fmaxf(mx, a);
    }
    mx = fmaxf(mx, __shfl_xor(mx, 16));
    mx = fmaxf(mx, __shfl_xor(mx, 32));

    float s0 = 0.f, s1 = 0.f;
#pragma unroll
    for (int kt = 0; kt < 16; ++kt) {
        float p0 = __expf(cv[kt][0] - mx);
        float p1 = __expf(cv[kt][1] - mx);
        float p2 = __expf(cv[kt][2] - mx);
        float p3 = __expf(cv[kt][3] - mx);
        cv[kt][0] = p0; cv[kt][1] = p1; cv[kt][2] = p2; cv[kt][3] = p3;
        s0 += p0 + p1;
        s1 += p2 + p3;
    }
    float sum = s0 + s1;
    sum += __shfl_xor(sum, 16);
    sum += __shfl_xor(sum, 32);
    const float rinv = 1.0f / sum;

    __syncthreads();  // all waves done reading K before P overwrites S

    // ---- normalized P (f16) to LDS; wave w writes exactly rows [w*16, w*16+16)
    const int qlocal = w * 16 + lm;
#pragma unroll
    for (int kt = 0; kt < 16; ++kt) {
        const int col0 = kt * 16 + g * 4;
        f16x4 pv4;
#pragma unroll
        for (int r = 0; r < 4; ++r) pv4[r] = (f16)(cv[kt][r] * rinv);
        *(f16x4*)&S[qlocal * 256 + SWZ(qlocal, col0)] = pv4;
    }
    // no barrier needed: each wave reads back only its own 16 rows below

    // ---- attn_out: contiguous 972-B row stores from S (lane l -> cols 4l..4l+3)
    float* dst = attn_out + (size_t)s * (T_DIM * T_DIM);
#pragma unroll
    for (int rr = 0; rr < 16; ++rr) {
        const int row = w * 16 + rr;
        const int qr = q0 + row;
        if (qr < T_DIM) {  // wave-uniform
            const int col = l * 4;
            f16x4 pv = *(const f16x4*)&S[row * 256 + SWZ(row, col)];
            float* p = dst + (size_t)qr * T_DIM + col;
            if (col + 3 < T_DIM) {          // lanes 0..59
                f32x4a o4;
#pragma unroll
                for (int r = 0; r < 4; ++r) o4[r] = (float)pv[r];
                *(f32x4a*)p = o4;
            } else if (col < T_DIM) {       // lane 60: cols 240..242
                p[0] = (float)pv[0]; p[1] = (float)pv[1]; p[2] = (float)pv[2];
            }
        }
    }

    // ---- PV: O[16 rows][32 e] per wave, V^T read direct from global (b128, L2-hot)
    const f16* vpS = ws_vpt + (size_t)s * (HD_DIM * 256);
    f32x4 o0 = {}, o1 = {};
    const int prow = w * 16 + lm;
#pragma unroll
    for (int kk = 0; kk < 8; ++kk) {
        f16x8 ap = *(const f16x8*)(&S[prow * 256 + SWZ(prow, kk * 32 + g * 8)]);
        f16x8 b0 = *(const f16x8*)(vpS + (size_t)(0 * 16 + lm) * 256 + kk * 32 + g * 8);
        f16x8 b1 = *(const f16x8*)(vpS + (size_t)(1 * 16 + lm) * 256 + kk * 32 + g * 8);
        o0 = __builtin_amdgcn_mfma_f32_16x16x32_f16(ap, b0, o0, 0, 0, 0);
        o1 = __builtin_amdgcn_mfma_f32_16x16x32_f16(ap, b1, o1, 0, 0, 0);
    }

    // store O to [m][256] f16 (input of final projection)
    int b = s / (H_DIM * J_DIM);
    int rem = s - b * (H_DIM * J_DIM);
    int h = rem / J_DIM;
    int jj = rem - h * J_DIM;
#pragma unroll
    for (int r = 0; r < 4; ++r) {
        int qr = q0 + w * 16 + g * 4 + r;
        if (qr >= T_DIM) continue;
        size_t m = (size_t)b * TJ + (size_t)qr * J_DIM + jj;
        ws_o[m * 256 + h * 32 + lm] = (f16)o0[r];
        ws_o[m * 256 + h * 32 + 16 + lm] = (f16)o1[r];
    }
}

// out[m,n] = sum_k O[m,k] * Wp[n,k] + bp[n], fp32 out
__global__ __launch_bounds__(256)
void outproj_kernel(const f16* __restrict__ ws_o, const f16* __restrict__ wpf,
                    const float* __restrict__ bp, float* __restrict__ out)
{
    const int tid = threadIdx.x;
    const int w = tid >> 6, l = tid & 63;
    const int lm = l & 15, g = l >> 4;
    const int m0 = blockIdx.x * 64;

    int m = m0 + w * 16 + lm;
    const bool mok = m < M_DIM;
    if (!mok) m = M_DIM - 1;
    const f16* Ab = ws_o + (size_t)m * C_DIM + g * 8;
    f16x8 af[8];
#pragma unroll
    for (int kk = 0; kk < 8; ++kk) af[kk] = *(const f16x8*)(Ab + kk * 32);

    f32x4 acc[16] = {};
#pragma unroll
    for (int nt = 0; nt < 16; ++nt) {
        const f16* Wb = wpf + (size_t)(nt * 16 + lm) * C_DIM + g * 8;
#pragma unroll
        for (int kk = 0; kk < 8; ++kk) {
            f16x8 bf = *(const f16x8*)(Wb + kk * 32);
            acc[nt] = __builtin_amdgcn_mfma_f32_16x16x32_f16(bf, af[kk], acc[nt], 0, 0, 0);
        }
    }

    if (mok) {
#pragma unroll
        for (int nt = 0; nt < 16; ++nt) {
            int n0 = nt * 16 + g * 4;
            f32x4a bv = *(const f32x4a*)(bp + n0);
            f32x4a o;
#pragma unroll
            for (int r = 0; r < 4; ++r) o[r] = acc[nt][r] + bv[r];
            *(f32x4a*)(out + (size_t)m * C_DIM + n0) = o;
        }
    }
}

extern "C" void kernel_launch(void* const* d_in, const int* in_sizes, int n_in,
                              void* d_out, int out_size, void* d_ws, size_t ws_size,
                              hipStream_t stream)
{
    const float* q  = (const float*)d_in[0];
    const float* kv = (const float*)d_in[1];
    const float* Wq = (const float*)d_in[2];
    const float* Wk = (const float*)d_in[3];
    const float* Wv = (const float*)d_in[4];
    const float* Wp = (const float*)d_in[5];
    const float* bp = (const float*)d_in[6];
    float* attn_out = (float*)d_out;
    float* out = attn_out + ATTN_SZ;
    f16* ws = (f16*)d_ws;

    wconv_kernel<<<dim3(1024), dim3(256), 0, stream>>>(Wq, Wk, Wv, Wp, ws + WF_OFF);

    dim3 gp((M_DIM + 63) / 64, 1);
    proj_kernel<<<gp, dim3(256), 0, stream>>>(q, ws + WF_OFF, ws + QP_OFF);

    dim3 gkv(4, B_DIM * J_DIM);
    kvproj_kernel<<<gkv, dim3(256), 0, stream>>>(kv, ws + WF_OFF, ws + KP_OFF, ws + VPT_OFF);

    dim3 ga(4, NSLICE);
    attn_kernel<<<ga, dim3(256), 0, stream>>>(ws + QP_OFF, ws + KP_OFF, ws + VPT_OFF,
                                              ws + O_OFF, attn_out);

    dim3 go((M_DIM + 63) / 64, 1);
    outproj_kernel<<<go, dim3(256), 0, stream>>>(ws + O_OFF, ws + WF_OFF + 3 * 65536, bp, out);
}